// Round 1
// baseline (216.230 us; speedup 1.0000x reference)
//
#include <hip/hip_runtime.h>

// Problem constants: B=4, N=2048, F=D=128, H=4.
#define NB 4
#define NN 2048
#define ND 128
#define NH 4

typedef short short8 __attribute__((ext_vector_type(8)));
typedef float floatx4 __attribute__((ext_vector_type(4)));

__device__ __forceinline__ short f2bf(float f){
  unsigned u = __float_as_uint(f);
  u += 0x7FFFu + ((u >> 16) & 1u);   // round-to-nearest-even
  return (short)(u >> 16);
}

// ---------------- K0: WT[d][f] = W[f][d]; attnT[h][e][d] = attn[h][d][e] (bf16) ----
__global__ void k0_transpose(const float* __restrict__ W, const float* __restrict__ attn,
                             short* __restrict__ WT, short* __restrict__ attnT){
  int mat = blockIdx.x;                       // 0 = W, 1..4 = attn heads
  const float* src = (mat == 0) ? W : (attn + (mat - 1) * 16384);
  short* dst = (mat == 0) ? WT : (attnT + (mat - 1) * 16384);
  for (int k = 0; k < 64; ++k){
    int idx = k * 256 + threadIdx.x;
    int r = idx >> 7, c = idx & 127;
    dst[idx] = f2bf(src[c * 128 + r]);
  }
}

// ---------------- K1: Xp = X @ W + bias  (bf16 out), MFMA gemm_bt vs WT -----------
__global__ __launch_bounds__(256) void k1_xp(const float* __restrict__ X,
                                             const short* __restrict__ WT,
                                             const float* __restrict__ bias,
                                             short* __restrict__ Xp){
  int bid = blockIdx.x;                       // 128 = 4b * 32 i-tiles
  int b = bid >> 5, i0 = (bid & 31) << 6;
  int t = threadIdx.x, w = t >> 6, lane = t & 63, lq = lane >> 4, lc = lane & 15;
  __shared__ __align__(16) short ldsB[16384]; // swizzled [16 fblk][128 d][8]
  #pragma unroll
  for (int c = 0; c < 8; ++c){
    int q = c * 256 + t; int fblk = q >> 7; int d = q & 127;
    *(short8*)&ldsB[q * 8] = *(const short8*)&WT[d * 128 + fblk * 8];
  }
  short8 af[4][4];
  #pragma unroll
  for (int ib = 0; ib < 4; ++ib)
    #pragma unroll
    for (int k = 0; k < 4; ++k){
      const float* xp = &X[(b * NN + i0 + ib * 16 + lc) * ND + k * 32 + lq * 8];
      short8 s;
      #pragma unroll
      for (int j = 0; j < 8; ++j) s[j] = f2bf(xp[j]);
      af[ib][k] = s;
    }
  __syncthreads();
  floatx4 acc[4][2];
  #pragma unroll
  for (int ib = 0; ib < 4; ++ib)
    #pragma unroll
    for (int eb = 0; eb < 2; ++eb) acc[ib][eb] = (floatx4){0.f, 0.f, 0.f, 0.f};
  #pragma unroll
  for (int eb = 0; eb < 2; ++eb)
    #pragma unroll
    for (int k = 0; k < 4; ++k){
      short8 bf = *(short8*)&ldsB[(k * 4 + lq) * 1024 + (w * 32 + eb * 16 + lc) * 8];
      #pragma unroll
      for (int ib = 0; ib < 4; ++ib)
        acc[ib][eb] = __builtin_amdgcn_mfma_f32_16x16x32_bf16(af[ib][k], bf, acc[ib][eb], 0, 0, 0);
    }
  #pragma unroll
  for (int ib = 0; ib < 4; ++ib)
    #pragma unroll
    for (int eb = 0; eb < 2; ++eb){
      int d = w * 32 + eb * 16 + lc;
      float bv = bias[d];
      #pragma unroll
      for (int r = 0; r < 4; ++r){
        int n = i0 + ib * 16 + lq * 4 + r;
        Xp[(b * NN + n) * ND + d] = f2bf(acc[ib][eb][r] + bv);
      }
    }
}

// ---------------- K1b: XpT[b][d][n] = Xp[b][n][d] (bf16, LDS tile transpose) ------
__global__ void k1b_transpose(const short* __restrict__ Xp, short* __restrict__ XpT){
  int bid = blockIdx.x;                       // 256 = 4b * 32 ntiles * 2 dtiles
  int b = bid >> 6; int rem = bid & 63;
  int n0 = (rem >> 1) << 6, d0 = (rem & 1) << 6;
  __shared__ short tile[64][65];
  int t = threadIdx.x;
  for (int k = 0; k < 16; ++k){
    int idx = k * 256 + t; int r = idx >> 6, c = idx & 63;
    tile[r][c] = Xp[(b * NN + n0 + r) * ND + d0 + c];
  }
  __syncthreads();
  for (int k = 0; k < 16; ++k){
    int idx = k * 256 + t; int r = idx >> 6, c = idx & 63;
    XpT[(b * ND + d0 + r) * NN + n0 + c] = tile[c][r];
  }
}

// ---------------- K2: Y[b][h] = Xp @ attn_h  (bf16 out), MFMA vs attnT ------------
__global__ __launch_bounds__(256) void k2_y(const short* __restrict__ Xp,
                                            const short* __restrict__ attnT,
                                            short* __restrict__ Y){
  int bid = blockIdx.x;                       // 512 = 4b * 4h * 32
  int it = bid & 31, h = (bid >> 5) & 3, b = bid >> 7;
  int i0 = it << 6;
  int t = threadIdx.x, w = t >> 6, lane = t & 63, lq = lane >> 4, lc = lane & 15;
  __shared__ __align__(16) short ldsB[16384]; // swizzled [16 dblk][128 e][8]
  const short* Bsrc = attnT + h * 16384;
  #pragma unroll
  for (int c = 0; c < 8; ++c){
    int q = c * 256 + t; int dblk = q >> 7; int e = q & 127;
    *(short8*)&ldsB[q * 8] = *(const short8*)&Bsrc[e * 128 + dblk * 8];
  }
  short8 af[4][4];
  #pragma unroll
  for (int ib = 0; ib < 4; ++ib)
    #pragma unroll
    for (int k = 0; k < 4; ++k)
      af[ib][k] = *(const short8*)&Xp[(b * NN + i0 + ib * 16 + lc) * ND + k * 32 + lq * 8];
  __syncthreads();
  floatx4 acc[4][2];
  #pragma unroll
  for (int ib = 0; ib < 4; ++ib)
    #pragma unroll
    for (int eb = 0; eb < 2; ++eb) acc[ib][eb] = (floatx4){0.f, 0.f, 0.f, 0.f};
  #pragma unroll
  for (int eb = 0; eb < 2; ++eb)
    #pragma unroll
    for (int k = 0; k < 4; ++k){
      short8 bf = *(short8*)&ldsB[(k * 4 + lq) * 1024 + (w * 32 + eb * 16 + lc) * 8];
      #pragma unroll
      for (int ib = 0; ib < 4; ++ib)
        acc[ib][eb] = __builtin_amdgcn_mfma_f32_16x16x32_bf16(af[ib][k], bf, acc[ib][eb], 0, 0, 0);
    }
  #pragma unroll
  for (int ib = 0; ib < 4; ++ib)
    #pragma unroll
    for (int eb = 0; eb < 2; ++eb){
      int e = w * 32 + eb * 16 + lc;
      #pragma unroll
      for (int r = 0; r < 4; ++r){
        int n = i0 + ib * 16 + lq * 4 + r;
        Y[((b * NH + h) * NN + n) * ND + e] = f2bf(acc[ib][eb][r]);
      }
    }
}

// ---------------- K3: fused  S = Y@Xp^T ; P = tanh(A*S) ; acc += P@Xp -------------
// grid 512 = (b, h, 64-row i-tile).  Mt = 64.  Waves split m (S phase) / d (PV).
__global__ __launch_bounds__(256, 2) void k3_fused(const short* __restrict__ Xp,
                                                   const short* __restrict__ XpT,
                                                   const short* __restrict__ Y,
                                                   const float* __restrict__ A,
                                                   float* __restrict__ heads){
  int bid = blockIdx.x;
  int it = bid & 31, h = (bid >> 5) & 3, b = bid >> 7;
  int i0 = it << 6;
  int t = threadIdx.x, w = t >> 6, lane = t & 63, lq = lane >> 4, lc = lane & 15;

  // Swizzled LDS layouts: every MFMA-fragment ds_read_b128 is lane-contiguous.
  __shared__ __align__(16) short ldsXp[8192];  // [16 dblk][64 m][8]  (16KB)
  __shared__ __align__(16) short ldsXpT[8192]; // [8 mblk][128 d][8]  (16KB)
  __shared__ __align__(16) short ldsP[4096];   // [8 mblk][64 i][8]   (8KB)

  // Y A-fragments for this (b,h,i-tile): pinned in registers for all 32 m-tiles.
  short8 yf[4][4];
  const short* Yb = Y + ((b * NH + h) * NN + i0) * ND;
  #pragma unroll
  for (int ib = 0; ib < 4; ++ib)
    #pragma unroll
    for (int k = 0; k < 4; ++k)
      yf[ib][k] = *(const short8*)&Yb[(ib * 16 + lc) * ND + k * 32 + lq * 8];

  floatx4 acc[4][2];
  #pragma unroll
  for (int ib = 0; ib < 4; ++ib)
    #pragma unroll
    for (int db = 0; db < 2; ++db) acc[ib][db] = (floatx4){0.f, 0.f, 0.f, 0.f};

  const int pblk = w * 2 + (lc >> 3);          // P-write m-block
  const int psub = lc & 7;

  for (int m0 = 0; m0 < NN; m0 += 64){
    __syncthreads();                            // previous PV done before restage
    // stage Xp m-tile (swizzled)
    const short* XpB = Xp + (b * NN + m0) * ND;
    #pragma unroll
    for (int c = 0; c < 4; ++c){
      int q = c * 256 + t; int dblk = q >> 6; int m = q & 63;
      *(short8*)&ldsXp[q * 8] = *(const short8*)&XpB[m * ND + dblk * 8];
    }
    // stage XpT m-slice (swizzled)
    const short* XpTB = XpT + b * ND * NN + m0;
    #pragma unroll
    for (int c = 0; c < 4; ++c){
      int q = c * 256 + t; int mblk = q >> 7; int d = q & 127;
      *(short8*)&ldsXpT[q * 8] = *(const short8*)&XpTB[d * NN + mblk * 8];
    }
    // prefetch A values for this tile (C-layout pattern, coalesced 64B rows)
    float av[4][4];
    const float* Ab = A + (b * NN + i0) * NN + m0 + w * 16 + lc;
    #pragma unroll
    for (int ib = 0; ib < 4; ++ib)
      #pragma unroll
      for (int r = 0; r < 4; ++r)
        av[ib][r] = Ab[(ib * 16 + lq * 4 + r) * NN];
    __syncthreads();                            // staging visible

    // S = Y @ Xp^T  (wave w owns m-columns [w*16, w*16+16))
    floatx4 S[4];
    #pragma unroll
    for (int ib = 0; ib < 4; ++ib) S[ib] = (floatx4){0.f, 0.f, 0.f, 0.f};
    #pragma unroll
    for (int k = 0; k < 4; ++k){
      short8 bf = *(short8*)&ldsXp[(k * 4 + lq) * 512 + (w * 16 + lc) * 8];
      #pragma unroll
      for (int ib = 0; ib < 4; ++ib)
        S[ib] = __builtin_amdgcn_mfma_f32_16x16x32_bf16(yf[ib][k], bf, S[ib], 0, 0, 0);
    }
    // P = tanh(A * S)  -> bf16 -> LDS (A-layout-friendly swizzle)
    #pragma unroll
    for (int ib = 0; ib < 4; ++ib)
      #pragma unroll
      for (int r = 0; r < 4; ++r){
        float x = av[ib][r] * S[ib][r];
        float e = __builtin_amdgcn_exp2f(x * 2.88539008177793f);   // e^{2x}
        float th = 1.f - 2.f * __builtin_amdgcn_rcpf(e + 1.f);     // tanh(x)
        ldsP[pblk * 512 + (ib * 16 + lq * 4 + r) * 8 + psub] = f2bf(th);
      }
    __syncthreads();                            // P visible

    // acc += P @ Xp   (wave w owns d-columns [w*32, w*32+32))
    #pragma unroll
    for (int kb = 0; kb < 2; ++kb){
      short8 pf[4];
      #pragma unroll
      for (int ib = 0; ib < 4; ++ib)
        pf[ib] = *(short8*)&ldsP[(kb * 4 + lq) * 512 + (ib * 16 + lc) * 8];
      #pragma unroll
      for (int db = 0; db < 2; ++db){
        short8 bf = *(short8*)&ldsXpT[(kb * 4 + lq) * 1024 + (w * 32 + db * 16 + lc) * 8];
        #pragma unroll
        for (int ib = 0; ib < 4; ++ib)
          acc[ib][db] = __builtin_amdgcn_mfma_f32_16x16x32_bf16(pf[ib], bf, acc[ib][db], 0, 0, 0);
      }
    }
  }
  // epilogue: write per-head aggregate
  float* Hb = heads + ((b * NH + h) * NN + i0) * ND;
  #pragma unroll
  for (int ib = 0; ib < 4; ++ib)
    #pragma unroll
    for (int db = 0; db < 2; ++db)
      #pragma unroll
      for (int r = 0; r < 4; ++r)
        Hb[(ib * 16 + lq * 4 + r) * ND + w * 32 + db * 16 + lc] = acc[ib][db][r];
}

// ---------------- K4: out = relu(relu(mean_h heads) + X) --------------------------
__global__ void k4_final(const float* __restrict__ heads, const float* __restrict__ X,
                         float* __restrict__ out){
  int idx = blockIdx.x * 256 + threadIdx.x;
  int f = idx * 4;
  int b = f >> 18;                              // 262144 = N*D per batch
  float4 a0 = *(const float4*)(heads + f + (3 * b + 0) * 262144);
  float4 a1 = *(const float4*)(heads + f + (3 * b + 1) * 262144);
  float4 a2 = *(const float4*)(heads + f + (3 * b + 2) * 262144);
  float4 a3 = *(const float4*)(heads + f + (3 * b + 3) * 262144);
  float4 xv = *(const float4*)(X + f);
  float4 o;
  o.x = fmaxf(fmaxf(0.25f * (a0.x + a1.x + a2.x + a3.x), 0.f) + xv.x, 0.f);
  o.y = fmaxf(fmaxf(0.25f * (a0.y + a1.y + a2.y + a3.y), 0.f) + xv.y, 0.f);
  o.z = fmaxf(fmaxf(0.25f * (a0.z + a1.z + a2.z + a3.z), 0.f) + xv.z, 0.f);
  o.w = fmaxf(fmaxf(0.25f * (a0.w + a1.w + a2.w + a3.w), 0.f) + xv.w, 0.f);
  *(float4*)(out + f) = o;
}

// ---------------- launch ----------------------------------------------------------
extern "C" void kernel_launch(void* const* d_in, const int* in_sizes, int n_in,
                              void* d_out, int out_size, void* d_ws, size_t ws_size,
                              hipStream_t stream) {
  const float* X    = (const float*)d_in[0];   // [4,2048,128]
  const float* A    = (const float*)d_in[1];   // [4,2048,2048]
  const float* W    = (const float*)d_in[2];   // [128,128]
  const float* bias = (const float*)d_in[3];   // [128]
  const float* attn = (const float*)d_in[4];   // [4,128,128]
  float* out = (float*)d_out;

  // workspace layout
  const size_t OFF_XP    = 0;                          // 2 MB bf16
  const size_t OFF_XPT   = (size_t)2 << 20;            // 2 MB bf16
  const size_t OFF_Y     = (size_t)4 << 20;            // 8 MB bf16
  const size_t OFF_HEADS = (size_t)12 << 20;           // 16 MB f32
  const size_t OFF_WT    = (size_t)28 << 20;           // 32 KB bf16
  const size_t OFF_ATTNT = OFF_WT + 32768;             // 128 KB bf16
  const size_t NEED = OFF_ATTNT + 131072;
  if (ws_size < NEED) return;                          // ws too small: bail (visible as failure)

  char* ws = (char*)d_ws;
  short* Xp    = (short*)(ws + OFF_XP);
  short* XpT   = (short*)(ws + OFF_XPT);
  short* Y     = (short*)(ws + OFF_Y);
  float* heads = (float*)(ws + OFF_HEADS);
  short* WT    = (short*)(ws + OFF_WT);
  short* attnT = (short*)(ws + OFF_ATTNT);

  k0_transpose<<<5, 256, 0, stream>>>(W, attn, WT, attnT);
  k1_xp<<<128, 256, 0, stream>>>(X, WT, bias, Xp);
  k1b_transpose<<<256, 256, 0, stream>>>(Xp, XpT);
  k2_y<<<512, 256, 0, stream>>>(Xp, attnT, Y);
  k3_fused<<<512, 256, 0, stream>>>(Xp, XpT, Y, A, heads);
  k4_final<<<1024, 256, 0, stream>>>(heads, X, out);
}

// Round 2
// 185.555 us; speedup vs baseline: 1.1653x; 1.1653x over previous
//
#include <hip/hip_runtime.h>

// Problem constants: B=4, N=2048, F=D=128, H=4.
#define NB 4
#define NN 2048
#define ND 128
#define NH 4

typedef short short8 __attribute__((ext_vector_type(8)));
typedef short short4v __attribute__((ext_vector_type(4)));
typedef float floatx4 __attribute__((ext_vector_type(4)));

__device__ __forceinline__ short f2bf(float f){
  unsigned u = __float_as_uint(f);
  u += 0x7FFFu + ((u >> 16) & 1u);   // round-to-nearest-even
  return (short)(u >> 16);
}
__device__ __forceinline__ float bf2f(short s){
  unsigned u = ((unsigned)(unsigned short)s) << 16;
  return __uint_as_float(u);
}

// ---------------- K0: WT[d][f] = W[f][d]; attnT[h][e][d] = attn[h][d][e] (bf16) ----
__global__ void k0_transpose(const float* __restrict__ W, const float* __restrict__ attn,
                             short* __restrict__ WT, short* __restrict__ attnT){
  int mat = blockIdx.x;                       // 0 = W, 1..4 = attn heads
  const float* src = (mat == 0) ? W : (attn + (mat - 1) * 16384);
  short* dst = (mat == 0) ? WT : (attnT + (mat - 1) * 16384);
  __shared__ short tile[128 * 130];
  int t = threadIdx.x;
  for (int k = 0; k < 64; ++k){               // coalesced read, transposed LDS write
    int idx = k * 256 + t;
    int r = idx >> 7, c = idx & 127;
    tile[c * 130 + r] = f2bf(src[idx]);
  }
  __syncthreads();
  for (int k = 0; k < 8; ++k){                // coalesced vector-ish write out
    int g = k * 256 + t;
    int r = g >> 4, c8 = g & 15;
    short8 v;
    #pragma unroll
    for (int j = 0; j < 8; ++j) v[j] = tile[r * 130 + c8 * 8 + j];
    *(short8*)&dst[r * 128 + c8 * 8] = v;
  }
}

// ---------------- K1: Xp = X @ W + bias  (bf16 out), MFMA gemm_bt vs WT -----------
__global__ __launch_bounds__(256) void k1_xp(const float* __restrict__ X,
                                             const short* __restrict__ WT,
                                             const float* __restrict__ bias,
                                             short* __restrict__ Xp){
  int bid = blockIdx.x;                       // 128 = 4b * 32 i-tiles
  int b = bid >> 5, i0 = (bid & 31) << 6;
  int t = threadIdx.x, w = t >> 6, lane = t & 63, lq = lane >> 4, lc = lane & 15;
  __shared__ __align__(16) short ldsB[16384]; // swizzled [16 fblk][128 d][8]
  #pragma unroll
  for (int c = 0; c < 8; ++c){
    int q = c * 256 + t; int fblk = q >> 7; int d = q & 127;
    *(short8*)&ldsB[q * 8] = *(const short8*)&WT[d * 128 + fblk * 8];
  }
  short8 af[4][4];
  #pragma unroll
  for (int ib = 0; ib < 4; ++ib)
    #pragma unroll
    for (int k = 0; k < 4; ++k){
      const float* xp = &X[(b * NN + i0 + ib * 16 + lc) * ND + k * 32 + lq * 8];
      float4 x0 = *(const float4*)xp;
      float4 x1 = *(const float4*)(xp + 4);
      short8 s;
      s[0]=f2bf(x0.x); s[1]=f2bf(x0.y); s[2]=f2bf(x0.z); s[3]=f2bf(x0.w);
      s[4]=f2bf(x1.x); s[5]=f2bf(x1.y); s[6]=f2bf(x1.z); s[7]=f2bf(x1.w);
      af[ib][k] = s;
    }
  __syncthreads();
  floatx4 acc[4][2];
  #pragma unroll
  for (int ib = 0; ib < 4; ++ib)
    #pragma unroll
    for (int eb = 0; eb < 2; ++eb) acc[ib][eb] = (floatx4){0.f, 0.f, 0.f, 0.f};
  #pragma unroll
  for (int eb = 0; eb < 2; ++eb)
    #pragma unroll
    for (int k = 0; k < 4; ++k){
      short8 bf = *(short8*)&ldsB[(k * 4 + lq) * 1024 + (w * 32 + eb * 16 + lc) * 8];
      #pragma unroll
      for (int ib = 0; ib < 4; ++ib)
        acc[ib][eb] = __builtin_amdgcn_mfma_f32_16x16x32_bf16(af[ib][k], bf, acc[ib][eb], 0, 0, 0);
    }
  #pragma unroll
  for (int ib = 0; ib < 4; ++ib)
    #pragma unroll
    for (int eb = 0; eb < 2; ++eb){
      int d = w * 32 + eb * 16 + lc;
      float bv = bias[d];
      #pragma unroll
      for (int r = 0; r < 4; ++r){
        int n = i0 + ib * 16 + lq * 4 + r;
        Xp[(b * NN + n) * ND + d] = f2bf(acc[ib][eb][r] + bv);
      }
    }
}

// ---------------- K1b: XpT[b][d][n] = Xp[b][n][d] (bf16, vectorized) ---------------
__global__ void k1b_transpose(const short* __restrict__ Xp, short* __restrict__ XpT){
  int bid = blockIdx.x;                       // 256 = 4b * 32 ntiles * 2 dtiles
  int b = bid >> 6; int rem = bid & 63;
  int n0 = (rem >> 1) << 6, d0 = (rem & 1) << 6;
  __shared__ short tile[64 * 66];             // [d][n], pad 66
  int t = threadIdx.x;
  #pragma unroll
  for (int c = 0; c < 2; ++c){
    int g = c * 256 + t; int r = g >> 3, c8 = g & 7;
    short8 v = *(const short8*)&Xp[(b * NN + n0 + r) * ND + d0 + c8 * 8];
    #pragma unroll
    for (int j = 0; j < 8; ++j) tile[(c8 * 8 + j) * 66 + r] = v[j];
  }
  __syncthreads();
  #pragma unroll
  for (int c = 0; c < 2; ++c){
    int g = c * 256 + t; int d = g >> 3, n8 = g & 7;
    short8 v;
    #pragma unroll
    for (int j = 0; j < 8; ++j) v[j] = tile[d * 66 + n8 * 8 + j];
    *(short8*)&XpT[(b * ND + d0 + d) * NN + n0 + n8 * 8] = v;
  }
}

// ---------------- K2: Y[b][h] = Xp @ attn_h  (bf16 out), MFMA vs attnT ------------
__global__ __launch_bounds__(256) void k2_y(const short* __restrict__ Xp,
                                            const short* __restrict__ attnT,
                                            short* __restrict__ Y){
  int bid = blockIdx.x;                       // 512 = 4b * 4h * 32
  int it = bid & 31, h = (bid >> 5) & 3, b = bid >> 7;
  int i0 = it << 6;
  int t = threadIdx.x, w = t >> 6, lane = t & 63, lq = lane >> 4, lc = lane & 15;
  __shared__ __align__(16) short ldsB[16384]; // swizzled [16 dblk][128 e][8]
  const short* Bsrc = attnT + h * 16384;
  #pragma unroll
  for (int c = 0; c < 8; ++c){
    int q = c * 256 + t; int dblk = q >> 7; int e = q & 127;
    *(short8*)&ldsB[q * 8] = *(const short8*)&Bsrc[e * 128 + dblk * 8];
  }
  short8 af[4][4];
  #pragma unroll
  for (int ib = 0; ib < 4; ++ib)
    #pragma unroll
    for (int k = 0; k < 4; ++k)
      af[ib][k] = *(const short8*)&Xp[(b * NN + i0 + ib * 16 + lc) * ND + k * 32 + lq * 8];
  __syncthreads();
  floatx4 acc[4][2];
  #pragma unroll
  for (int ib = 0; ib < 4; ++ib)
    #pragma unroll
    for (int eb = 0; eb < 2; ++eb) acc[ib][eb] = (floatx4){0.f, 0.f, 0.f, 0.f};
  #pragma unroll
  for (int eb = 0; eb < 2; ++eb)
    #pragma unroll
    for (int k = 0; k < 4; ++k){
      short8 bf = *(short8*)&ldsB[(k * 4 + lq) * 1024 + (w * 32 + eb * 16 + lc) * 8];
      #pragma unroll
      for (int ib = 0; ib < 4; ++ib)
        acc[ib][eb] = __builtin_amdgcn_mfma_f32_16x16x32_bf16(af[ib][k], bf, acc[ib][eb], 0, 0, 0);
    }
  #pragma unroll
  for (int ib = 0; ib < 4; ++ib)
    #pragma unroll
    for (int eb = 0; eb < 2; ++eb){
      int e = w * 32 + eb * 16 + lc;
      #pragma unroll
      for (int r = 0; r < 4; ++r){
        int n = i0 + ib * 16 + lq * 4 + r;
        Y[((b * NH + h) * NN + n) * ND + e] = f2bf(acc[ib][eb][r]);
      }
    }
}

// ---------------- K3: fused  S^T = Xp@Y^T (4 heads) ; Pbar = 0.25*Σ tanh(A*S) ;
//                  part += Pbar @ Xp   (split-precision Pbar, 1 barrier/iter) ------
// grid 2048 = (ms 4, b 4, 128 i-tiles of 16 rows). Each block: m-range ms*512..+512.
__global__ __launch_bounds__(256, 3) void k3_fused(const short* __restrict__ Xp,
                                                   const short* __restrict__ XpT,
                                                   const short* __restrict__ Y,
                                                   const float* __restrict__ A,
                                                   float* __restrict__ part){
  int bid = blockIdx.x;
  int it = bid & 127, b = (bid >> 7) & 3, ms = bid >> 9;
  int i0 = it << 4;
  int t = threadIdx.x, w = t >> 6, lane = t & 63, lq = lane >> 4, lc = lane & 15;

  // double-buffered LDS; padded XpT stride (1040) keeps staging writes 2-way max
  __shared__ __align__(16) short ldsXpT[2][8320];  // [8 mb][128 d][8], stride 1040
  __shared__ __align__(16) short ldsPh[2][1024];   // [8 mb][16 i][8]
  __shared__ __align__(16) short ldsPl[2][1024];

  // Y B-frags pinned: all 4 heads, rows i0..i0+16, full 128 d
  short8 yf[4][4];
  #pragma unroll
  for (int h = 0; h < 4; ++h)
    #pragma unroll
    for (int k = 0; k < 4; ++k)
      yf[h][k] = *(const short8*)&Y[((b * NH + h) * NN + i0 + lc) * ND + k * 32 + lq * 8];

  floatx4 acc[2];
  acc[0] = (floatx4){0.f,0.f,0.f,0.f};
  acc[1] = (floatx4){0.f,0.f,0.f,0.f};

  const int mbase = ms << 9;                       // 512 m per block
  const int poff = (w * 2 + (lq >> 1)) * 128 + lc * 8 + (lq & 1) * 4;

  for (int itn = 0; itn < 8; ++itn){
    int p = itn & 1;
    int m0 = mbase + itn * 64;
    // stage XpT slice [128 d][64 m] -> swizzled LDS (coalesced 128B/row-group)
    const short* src = XpT + b * (ND * NN) + m0;
    #pragma unroll
    for (int c = 0; c < 4; ++c){
      int q = c * 256 + t; int d = q >> 3, mb = q & 7;
      *(short8*)&ldsXpT[p][mb * 1040 + d * 8] = *(const short8*)&src[d * NN + mb * 8];
    }
    // Xp A-frags for S^T, direct from global (L2-resident)
    short8 xpf[4];
    const short* xr = Xp + (b * NN + m0 + w * 16 + lc) * ND;
    #pragma unroll
    for (int k = 0; k < 4; ++k) xpf[k] = *(const short8*)&xr[k * 32 + lq * 8];
    // adjacency: one float4 per lane covers this wave's 4 m-rows at col i0+lc
    floatx4 av = *(const floatx4*)&A[(b * NN + i0 + lc) * NN + m0 + w * 16 + lq * 4];

    // S^T per head (no LDS!), tanh, head-mean in-register
    float psum[4] = {0.f, 0.f, 0.f, 0.f};
    #pragma unroll
    for (int h = 0; h < 4; ++h){
      floatx4 S = (floatx4){0.f,0.f,0.f,0.f};
      #pragma unroll
      for (int k = 0; k < 4; ++k)
        S = __builtin_amdgcn_mfma_f32_16x16x32_bf16(xpf[k], yf[h][k], S, 0, 0, 0);
      #pragma unroll
      for (int r = 0; r < 4; ++r){
        float x = av[r] * S[r];
        float e = __builtin_amdgcn_exp2f(x * 2.885390081777926f);  // e^{2x}
        psum[r] += 1.f - 2.f * __builtin_amdgcn_rcpf(e + 1.f);     // tanh
      }
    }
    short4v hi4, lo4;
    #pragma unroll
    for (int r = 0; r < 4; ++r){
      float pb = 0.25f * psum[r];
      short h16 = f2bf(pb);
      hi4[r] = h16;
      lo4[r] = f2bf(pb - bf2f(h16));
    }
    *(short4v*)&ldsPh[p][poff] = hi4;
    *(short4v*)&ldsPl[p][poff] = lo4;
    __syncthreads();                               // the ONLY barrier per iter

    // PV: acc += (Phi + Plo) @ Xp ; wave w owns d-range [w*32, w*32+32)
    #pragma unroll
    for (int kb = 0; kb < 2; ++kb){
      short8 ph = *(short8*)&ldsPh[p][(kb * 4 + lq) * 128 + lc * 8];
      short8 pl = *(short8*)&ldsPl[p][(kb * 4 + lq) * 128 + lc * 8];
      #pragma unroll
      for (int db = 0; db < 2; ++db){
        short8 bfr = *(short8*)&ldsXpT[p][(kb * 4 + lq) * 1040 + (w * 32 + db * 16 + lc) * 8];
        acc[db] = __builtin_amdgcn_mfma_f32_16x16x32_bf16(ph, bfr, acc[db], 0, 0, 0);
        acc[db] = __builtin_amdgcn_mfma_f32_16x16x32_bf16(pl, bfr, acc[db], 0, 0, 0);
      }
    }
  }
  // epilogue: partial (per-ms) tile, mean factor already folded into Pbar
  float* dst = part + (size_t)ms * 1048576 + (b * NN + i0) * ND;
  #pragma unroll
  for (int db = 0; db < 2; ++db)
    #pragma unroll
    for (int r = 0; r < 4; ++r)
      dst[(lq * 4 + r) * ND + w * 32 + db * 16 + lc] = acc[db][r];
}

// ---------------- K4: out = relu(relu(Σ ms-partials) + X) -------------------------
__global__ void k4_final(const float* __restrict__ part, const float* __restrict__ X,
                         float* __restrict__ out){
  int f = (blockIdx.x * 256 + threadIdx.x) * 4;
  float4 s0 = *(const float4*)(part + f);
  float4 s1 = *(const float4*)(part + 1048576 + f);
  float4 s2 = *(const float4*)(part + 2097152 + f);
  float4 s3 = *(const float4*)(part + 3145728 + f);
  float4 xv = *(const float4*)(X + f);
  float4 o;
  o.x = fmaxf(fmaxf(s0.x + s1.x + s2.x + s3.x, 0.f) + xv.x, 0.f);
  o.y = fmaxf(fmaxf(s0.y + s1.y + s2.y + s3.y, 0.f) + xv.y, 0.f);
  o.z = fmaxf(fmaxf(s0.z + s1.z + s2.z + s3.z, 0.f) + xv.z, 0.f);
  o.w = fmaxf(fmaxf(s0.w + s1.w + s2.w + s3.w, 0.f) + xv.w, 0.f);
  *(float4*)(out + f) = o;
}

// ---------------- launch ----------------------------------------------------------
extern "C" void kernel_launch(void* const* d_in, const int* in_sizes, int n_in,
                              void* d_out, int out_size, void* d_ws, size_t ws_size,
                              hipStream_t stream) {
  const float* X    = (const float*)d_in[0];   // [4,2048,128]
  const float* A    = (const float*)d_in[1];   // [4,2048,2048]
  const float* W    = (const float*)d_in[2];   // [128,128]
  const float* bias = (const float*)d_in[3];   // [128]
  const float* attn = (const float*)d_in[4];   // [4,128,128]
  float* out = (float*)d_out;

  // workspace layout
  const size_t OFF_XP    = 0;                          // 2 MB bf16
  const size_t OFF_XPT   = (size_t)2 << 20;            // 2 MB bf16
  const size_t OFF_Y     = (size_t)4 << 20;            // 8 MB bf16
  const size_t OFF_PART  = (size_t)12 << 20;           // 16 MB f32 (4 partials)
  const size_t OFF_WT    = (size_t)28 << 20;           // 32 KB bf16
  const size_t OFF_ATTNT = OFF_WT + 32768;             // 128 KB bf16
  const size_t NEED = OFF_ATTNT + 131072;
  if (ws_size < NEED) return;

  char* ws = (char*)d_ws;
  short* Xp    = (short*)(ws + OFF_XP);
  short* XpT   = (short*)(ws + OFF_XPT);
  short* Y     = (short*)(ws + OFF_Y);
  float* part  = (float*)(ws + OFF_PART);
  short* WT    = (short*)(ws + OFF_WT);
  short* attnT = (short*)(ws + OFF_ATTNT);

  k0_transpose<<<5, 256, 0, stream>>>(W, attn, WT, attnT);
  k1_xp<<<128, 256, 0, stream>>>(X, WT, bias, Xp);
  k1b_transpose<<<256, 256, 0, stream>>>(Xp, XpT);
  k2_y<<<512, 256, 0, stream>>>(Xp, attnT, Y);
  k3_fused<<<2048, 256, 0, stream>>>(Xp, XpT, Y, A, part);
  k4_final<<<1024, 256, 0, stream>>>(part, X, out);
}